// Round 9
// baseline (324.555 us; speedup 1.0000x reference)
//
#include <hip/hip_runtime.h>
#include <hip/hip_bf16.h>
#include <stdint.h>

// B=2, S=2048, D=1024, H=16, DK=64
typedef __bf16 bf16x8 __attribute__((ext_vector_type(8)));
typedef float f32x4 __attribute__((ext_vector_type(4)));

#define QSCALE 0.1803368801111244f  // (1/8) * log2(e): softmax via exp2

__device__ __forceinline__ void gld16(const void* g, void* l) {
  // async global->LDS, 16B/lane. LDS dest must be wave-uniform base + lane*16.
  __builtin_amdgcn_global_load_lds(
      (__attribute__((address_space(1))) void*)(uintptr_t)(g),
      (__attribute__((address_space(3))) void*)(l), 16, 0, 0);
}

// ---------------- cast f32 -> bf16 (7 tensors, one launch) ----------------
struct CastArgs {
  const float* src[7];
  __bf16* dst[7];
  int n[7];
};

__global__ __launch_bounds__(256) void cast_bf16_kernel(CastArgs a) {
  const int t = blockIdx.y;
  const int i = (blockIdx.x * 256 + threadIdx.x) * 8;
  if (i >= a.n[t]) return;
  const float4* s = (const float4*)(a.src[t] + i);
  float4 v0 = s[0], v1 = s[1];
  bf16x8 o;
  o[0] = (__bf16)v0.x; o[1] = (__bf16)v0.y; o[2] = (__bf16)v0.z; o[3] = (__bf16)v0.w;
  o[4] = (__bf16)v1.x; o[5] = (__bf16)v1.y; o[6] = (__bf16)v1.z; o[7] = (__bf16)v1.w;
  *(bf16x8*)(a.dst[t] + i) = o;
}

// ---------------- fused Q/K/V projection GEMM (double-buffered) ----------
// v9: 2-barrier drain structure -> attn-style dbuf: prefetch K-tile kk+1 in
// flight across the whole compute of tile kk; ONE barrier per iteration.
// z=0: Q = xq @ Wq^T (scale QSCALE) -> [b][h][s][dk]
// z=1: K = xk @ Wk^T               -> [b][h][s][dk]
// z=2: V^T = Wv @ xv^T             -> [b][h][dk][s]
struct QkvArgs {
  const __bf16* A[3];
  const __bf16* B[3];
  const float* bias[3];
  __bf16* out[3];
};

__global__ __launch_bounds__(256) void qkv_gemm(QkvArgs args) {
  __shared__ __align__(16) __bf16 As[2][128 * 32];
  __shared__ __align__(16) __bf16 Bs[2][128 * 32];
  const int tid = threadIdx.x;
  const int z = blockIdx.y;
  const int bx = blockIdx.x;
  const int m0 = (z < 2 ? (bx >> 3) : (bx & 7)) * 128;
  const int n0 = (z < 2 ? (bx & 7) : (bx >> 3)) * 128;
  const __bf16* A = args.A[z];
  const __bf16* B = args.B[z];
  const float* bias = args.bias[z];
  __bf16* out = args.out[z];
  const float scale = (z == 0) ? QSCALE : 1.0f;

  const int lane = tid & 63, wid = tid >> 6;
  const int wm = (wid & 1) * 64, wn = (wid >> 1) * 64;
  const int l16 = lane & 15, quad = lane >> 4;

  const int sc = (tid & 3) ^ ((tid >> 2) & 3);  // swizzled source chunk
  const __bf16* ga = A + (size_t)(m0 + (tid >> 2)) * 1024 + sc * 8;
  const __bf16* gb = B + (size_t)(n0 + (tid >> 2)) * 1024 + sc * 8;
  char* lA = (char*)As + tid * 16;
  char* lB = (char*)Bs + tid * 16;
  const int a_off = (wm + l16) * 64 + ((quad ^ (l16 & 3)) * 16);
  const int b_off = (wn + l16) * 64 + ((quad ^ (l16 & 3)) * 16);

  f32x4 acc[4][4] = {};

  // prologue: stage K-tile 0 into buffer 0
  gld16(ga, lA);
  gld16(ga + 64 * 1024, lA + 4096);
  gld16(gb, lB);
  gld16(gb + 64 * 1024, lB + 4096);
  __syncthreads();

  for (int kk = 0; kk < 32; ++kk) {
    const int cur = kk & 1;
    if (kk < 31) {  // prefetch tile kk+1 into alternate buffer (in flight)
      const int nb = cur ^ 1;
      gld16(ga + (kk + 1) * 32, lA + nb * 8192);
      gld16(ga + (kk + 1) * 32 + 64 * 1024, lA + nb * 8192 + 4096);
      gld16(gb + (kk + 1) * 32, lB + nb * 8192);
      gld16(gb + (kk + 1) * 32 + 64 * 1024, lB + nb * 8192 + 4096);
    }
    bf16x8 af[4], bfr[4];
#pragma unroll
    for (int mi = 0; mi < 4; ++mi)
      af[mi] = *(const bf16x8*)((const char*)As + cur * 8192 + a_off + mi * 1024);
#pragma unroll
    for (int ni = 0; ni < 4; ++ni)
      bfr[ni] = *(const bf16x8*)((const char*)Bs + cur * 8192 + b_off + ni * 1024);
#pragma unroll
    for (int mi = 0; mi < 4; ++mi)
#pragma unroll
      for (int ni = 0; ni < 4; ++ni)
        acc[mi][ni] = __builtin_amdgcn_mfma_f32_16x16x32_bf16(af[mi], bfr[ni],
                                                              acc[mi][ni], 0, 0, 0);
    __syncthreads();  // readers done + prefetch (vmcnt) drained
  }

  if (z < 2) {  // token-major -> [b][h][s][dk]
#pragma unroll
    for (int ni = 0; ni < 4; ++ni) {
      const int col = n0 + wn + ni * 16 + l16;
      const int h = col >> 6, dk = col & 63;
      const float bb = bias[col];
#pragma unroll
      for (int mi = 0; mi < 4; ++mi)
#pragma unroll
        for (int r = 0; r < 4; ++r) {
          const int row = m0 + wm + mi * 16 + quad * 4 + r;
          const int b = row >> 11, s = row & 2047;
          out[((size_t)(b * 16 + h) * 2048 + s) * 64 + dk] =
              (__bf16)((acc[mi][ni][r] + bb) * scale);
        }
    }
  } else {  // V: A=W (m=feature), B=X (n=token); store Vt[b][h][dk][s]
#pragma unroll
    for (int mi = 0; mi < 4; ++mi)
#pragma unroll
      for (int r = 0; r < 4; ++r) {
        const int rowm = m0 + wm + mi * 16 + quad * 4 + r;
        const int h = rowm >> 6, dk = rowm & 63;
        const float bb = bias[rowm];
#pragma unroll
        for (int ni = 0; ni < 4; ++ni) {
          const int coln = n0 + wn + ni * 16 + l16;
          const int b = coln >> 11, s = coln & 2047;
          out[((size_t)(b * 16 + h) * 64 + dk) * 2048 + s] =
              (__bf16)(acc[mi][ni][r] + bb);
        }
      }
  }
}

// ---------------- output projection GEMM (f32 out, double-buffered) ------
__global__ __launch_bounds__(256) void gemm_out(const __bf16* __restrict__ A,
                                                const __bf16* __restrict__ B,
                                                const float* __restrict__ bias,
                                                float* __restrict__ out) {
  __shared__ __align__(16) __bf16 As[2][128 * 32];
  __shared__ __align__(16) __bf16 Bs[2][128 * 32];
  const int tid = threadIdx.x;
  const int m0 = blockIdx.y * 128;
  const int n0 = blockIdx.x * 128;
  const int lane = tid & 63, wid = tid >> 6;
  const int wm = (wid & 1) * 64, wn = (wid >> 1) * 64;
  const int l16 = lane & 15, quad = lane >> 4;

  const int sc = (tid & 3) ^ ((tid >> 2) & 3);
  const __bf16* ga = A + (size_t)(m0 + (tid >> 2)) * 1024 + sc * 8;
  const __bf16* gb = B + (size_t)(n0 + (tid >> 2)) * 1024 + sc * 8;
  char* lA = (char*)As + tid * 16;
  char* lB = (char*)Bs + tid * 16;
  const int a_off = (wm + l16) * 64 + ((quad ^ (l16 & 3)) * 16);
  const int b_off = (wn + l16) * 64 + ((quad ^ (l16 & 3)) * 16);

  f32x4 acc[4][4] = {};

  gld16(ga, lA);
  gld16(ga + 64 * 1024, lA + 4096);
  gld16(gb, lB);
  gld16(gb + 64 * 1024, lB + 4096);
  __syncthreads();

  for (int kk = 0; kk < 32; ++kk) {
    const int cur = kk & 1;
    if (kk < 31) {
      const int nb = cur ^ 1;
      gld16(ga + (kk + 1) * 32, lA + nb * 8192);
      gld16(ga + (kk + 1) * 32 + 64 * 1024, lA + nb * 8192 + 4096);
      gld16(gb + (kk + 1) * 32, lB + nb * 8192);
      gld16(gb + (kk + 1) * 32 + 64 * 1024, lB + nb * 8192 + 4096);
    }
    bf16x8 af[4], bfr[4];
#pragma unroll
    for (int mi = 0; mi < 4; ++mi)
      af[mi] = *(const bf16x8*)((const char*)As + cur * 8192 + a_off + mi * 1024);
#pragma unroll
    for (int ni = 0; ni < 4; ++ni)
      bfr[ni] = *(const bf16x8*)((const char*)Bs + cur * 8192 + b_off + ni * 1024);
#pragma unroll
    for (int mi = 0; mi < 4; ++mi)
#pragma unroll
      for (int ni = 0; ni < 4; ++ni)
        acc[mi][ni] = __builtin_amdgcn_mfma_f32_16x16x32_bf16(af[mi], bfr[ni],
                                                              acc[mi][ni], 0, 0, 0);
    __syncthreads();
  }

#pragma unroll
  for (int ni = 0; ni < 4; ++ni) {
    const int col = n0 + wn + ni * 16 + l16;
    const float bb = bias[col];
#pragma unroll
    for (int mi = 0; mi < 4; ++mi)
#pragma unroll
      for (int r = 0; r < 4; ++r) {
        const int row = m0 + wm + mi * 16 + quad * 4 + r;
        out[(size_t)row * 1024 + col] = acc[mi][ni][r] + bb;
      }
  }
}

// ---------------- flash attention (v6 exact revert) -----------------------
// v7/v8 post-mortem: dual-sub-tile structure spilled (~48B/thread scratch,
// WRITE 8.2->20.5MB) and LOWERED MfmaUtil -> falsified; revert to v6 (100.5us).
//  * SWAPPED QK^T: p2 = mfma(K, Q) -> each lane holds P for its own q-row.
//  * K rows staged through sigma(m) -> P lands in PV A-frag order, V natural.
//  * g folds into the pack: pa[j] = (bf16)(em * g); lp one scalar/lane.
__global__ __launch_bounds__(512, 4) void attn_kernel(
    const __bf16* __restrict__ Qh, const __bf16* __restrict__ Kh,
    const __bf16* __restrict__ Vt, const float* __restrict__ gprob,
    const int* __restrict__ maskp, __bf16* __restrict__ xb) {
  __shared__ __align__(16) __bf16 Ks[2][64 * 64];
  __shared__ __align__(16) __bf16 Vs[2][64 * 64];  // Vt tile: [dk][s_rel]
  __shared__ unsigned long long mbits[32];

  const int tid = threadIdx.x;
  const int qt = blockIdx.x, bh = blockIdx.y;  // qt 0..15 (128 q-rows each)
  const int b = bh >> 4, h = bh & 15;
  const int q0 = qt * 128;
  const int lane = tid & 63, wid = tid >> 6, l16 = lane & 15, quad = lane >> 4;
  const size_t head_off = (size_t)bh * (2048 * 64);

  const int srow = tid >> 3;                 // staging row 0..63 (512 threads)
  const int sc8 = (tid & 7) ^ (srow & 7);    // swizzled source chunk
  const int fxor = (l16 & 7);                // frag-read chunk xor

  // sigma(m): K-row staging permutation making swapped-QK P registers land in
  // PV A-frag order.
  const int sig = ((srow & 16) << 1) + ((srow & 12) << 1) + ((srow & 32) >> 3) +
                  (srow & 3);

  const __bf16* gk0 = Kh + head_off + (size_t)sig * 64 + sc8 * 8;
  const __bf16* gv0 = Vt + head_off + (size_t)srow * 2048 + sc8 * 8;

  // prologue staging: K/V tile 0 into buffer 0 (one gld16 each, 512 thr x 16B)
  gld16(gk0, (char*)Ks + tid * 16);
  gld16(gv0, (char*)Vs + tid * 16);

  // Q B-fragments direct from global (col = q0+wid*16+l16, dk chunks quad*8, +32)
  bf16x8 aq[2];
  {
    const __bf16* gq = Qh + head_off + (size_t)(q0 + wid * 16 + l16) * 64 + quad * 8;
    aq[0] = *(const bf16x8*)(gq);
    aq[1] = *(const bf16x8*)(gq + 32);
  }

  int irow[4];
#pragma unroll
  for (int r = 0; r < 4; ++r) irow[r] = q0 + wid * 16 + quad * 4 + r;

  // g for lane's q-row (q0+wid*16+l16), cols quad*8+{0..7} and +32 (A-frag order)
  const float* gpl = gprob + (size_t)b * 2048 * 2048 +
                     (size_t)(q0 + wid * 16 + l16) * 2048 + quad * 8;
  float4 g0 = *(const float4*)(gpl);
  float4 g1 = *(const float4*)(gpl + 4);
  float4 g2 = *(const float4*)(gpl + 32);
  float4 g3 = *(const float4*)(gpl + 36);

  // one-time mask ballot: mbits[kt] bit j = mask[b][kt*64+j]; 8 waves x 4
  {
    const int* mr = maskp + b * 2048;
#pragma unroll
    for (int t = 0; t < 4; ++t) {
      const int kt2 = wid * 4 + t;
      const int mv = mr[kt2 * 64 + lane];
      const unsigned long long bal = __ballot(mv != 0);
      if (lane == 0) mbits[kt2] = bal;
    }
  }
  __syncthreads();  // drains prologue staging (vmcnt0) + mbits visible

  f32x4 o[4] = {};
  float lp = 0.f;

  // diagonal k-tile for this wave's 16 q-rows (wave-uniform)
  const int dkt = qt * 2 + (wid >> 2);
  // lane's q-row rel. to the 64-wide k-tile; diag iff kqbase == kbase(ni,r)
  const int kqbase = (wid & 3) * 16 + l16 - quad * 8;

  for (int kt = 0; kt < 32; ++kt) {
    const int cur = kt & 1;
    float4 gn0, gn1, gn2, gn3;
    if (kt < 31) {  // prefetch K/V tile kt+1 into alternate buffer + g(kt+1)
      const int nb = cur ^ 1;
      gld16(gk0 + (kt + 1) * 4096, (char*)Ks + nb * 8192 + tid * 16);
      gld16(gv0 + (kt + 1) * 64, (char*)Vs + nb * 8192 + tid * 16);
      const float* gn = gpl + (kt + 1) * 64;
      gn0 = *(const float4*)(gn);
      gn1 = *(const float4*)(gn + 4);
      gn2 = *(const float4*)(gn + 32);
      gn3 = *(const float4*)(gn + 36);
    }

    // mask bits for this k-tile, shifted to this lane's k-window
    const unsigned long long sh = mbits[kt] >> (quad * 8);
    const uint32_t shlo = (uint32_t)sh, shhi = (uint32_t)(sh >> 32);

    // QK^T SWAPPED: p2[ni][r] = P[q=own row][k = sigma-staged] in log2 domain
    f32x4 p2[4] = {};
#pragma unroll
    for (int kh = 0; kh < 2; ++kh)
#pragma unroll
      for (int ni = 0; ni < 4; ++ni) {
        bf16x8 bk = *(const bf16x8*)((const char*)Ks + cur * 8192 +
                                     (ni * 16 + l16) * 128 +
                                     (((kh * 4 + quad) ^ fxor) * 16));
        p2[ni] = __builtin_amdgcn_mfma_f32_16x16x32_bf16(bk, aq[kh], p2[ni], 0, 0, 0);
      }

    // softmax + g fold + pack straight into PV A-fragments.
    // element (ni,r) holds k' = (ni&1)*32 + quad*8 + (ni>>1)*4 + r
    const float gfl[16] = {g0.x, g0.y, g0.z, g0.w, g1.x, g1.y, g1.z, g1.w,
                           g2.x, g2.y, g2.z, g2.w, g3.x, g3.y, g3.z, g3.w};
    bf16x8 pa0, pa1;
    if (kt != dkt) {
#pragma unroll
      for (int ni = 0; ni < 4; ++ni)
#pragma unroll
        for (int r = 0; r < 4; ++r) {
          const int j = ((ni >> 1) << 2) + r;
          const float e = __builtin_exp2f(p2[ni][r]);
          const bool mk = (((ni & 1) ? shhi : shlo) >> j) & 1;
          const float em = mk ? e : 0.f;
          lp += em;
          const float pg = em * gfl[(ni & 1) * 8 + j];
          if (ni & 1) pa1[j] = (__bf16)pg; else pa0[j] = (__bf16)pg;
        }
    } else {  // diagonal tile: always attend to self
#pragma unroll
      for (int ni = 0; ni < 4; ++ni)
#pragma unroll
        for (int r = 0; r < 4; ++r) {
          const int j = ((ni >> 1) << 2) + r;
          const float e = __builtin_exp2f(p2[ni][r]);
          const bool mk = (((ni & 1) ? shhi : shlo) >> j) & 1;
          const bool diag = (kqbase == ((ni & 1) * 32 + j));
          const float em = (mk || diag) ? e : 0.f;
          lp += em;
          const float pg = em * gfl[(ni & 1) * 8 + j];
          if (ni & 1) pa1[j] = (__bf16)pg; else pa0[j] = (__bf16)pg;
        }
    }

    // O += (P .* g) @ V, P directly from registers (no LDS roundtrip)
#pragma unroll
    for (int kh = 0; kh < 2; ++kh) {
      const bf16x8 pa = kh ? pa1 : pa0;
#pragma unroll
      for (int ni = 0; ni < 4; ++ni) {
        bf16x8 bv = *(const bf16x8*)((const char*)Vs + cur * 8192 +
                                     (ni * 16 + l16) * 128 +
                                     (((kh * 4 + quad) ^ fxor) * 16));
        o[ni] = __builtin_amdgcn_mfma_f32_16x16x32_bf16(pa, bv, o[ni], 0, 0, 0);
      }
    }

    if (kt < 31) { g0 = gn0; g1 = gn1; g2 = gn2; g3 = gn3; }
    __syncthreads();  // end of iter: prev readers done + prefetch drained
  }

  // lp: lane holds partial sum for q-row (l16); total over the 4 quads, then
  // redistribute to output rows quad*4+r and write x = O / l
  lp += __shfl_xor(lp, 16);
  lp += __shfl_xor(lp, 32);
  float rinv[4];
#pragma unroll
  for (int r = 0; r < 4; ++r) rinv[r] = 1.f / __shfl(lp, quad * 4 + r);
#pragma unroll
  for (int ni = 0; ni < 4; ++ni) {
    const int dk = ni * 16 + l16;
#pragma unroll
    for (int r = 0; r < 4; ++r) {
      const float val = o[ni][r] * rinv[r];
      xb[((size_t)(b * 2048 + irow[r])) * 1024 + h * 64 + dk] = (__bf16)val;
    }
  }
}

extern "C" void kernel_launch(void* const* d_in, const int* in_sizes, int n_in,
                              void* d_out, int out_size, void* d_ws, size_t ws_size,
                              hipStream_t stream) {
  const float* query = (const float*)d_in[0];
  const float* key_  = (const float*)d_in[1];
  const float* value = (const float*)d_in[2];
  const float* gprob = (const float*)d_in[3];
  const int*   maskp = (const int*)d_in[4];
  const float* Wq = (const float*)d_in[5];
  const float* bq = (const float*)d_in[6];
  const float* Wk = (const float*)d_in[7];
  const float* bk = (const float*)d_in[8];
  const float* Wv = (const float*)d_in[9];
  const float* bv = (const float*)d_in[10];
  const float* Wo = (const float*)d_in[11];
  const float* bo = (const float*)d_in[12];

  char* ws = (char*)d_ws;
  const size_t MB = 1 << 20;
  __bf16* qb  = (__bf16*)(ws + 0 * MB);
  __bf16* kb  = (__bf16*)(ws + 8 * MB);
  __bf16* vb  = (__bf16*)(ws + 16 * MB);
  __bf16* Wqb = (__bf16*)(ws + 24 * MB);
  __bf16* Wkb = (__bf16*)(ws + 26 * MB);
  __bf16* Wvb = (__bf16*)(ws + 28 * MB);
  __bf16* Wob = (__bf16*)(ws + 30 * MB);
  __bf16* Qh  = (__bf16*)(ws + 32 * MB);
  __bf16* Kh  = (__bf16*)(ws + 40 * MB);
  __bf16* Vt  = (__bf16*)(ws + 48 * MB);
  __bf16* xb  = (__bf16*)(ws + 56 * MB);

  CastArgs ca;
  ca.src[0] = query; ca.dst[0] = qb;  ca.n[0] = 4194304;
  ca.src[1] = key_;  ca.dst[1] = kb;  ca.n[1] = 4194304;
  ca.src[2] = value; ca.dst[2] = vb;  ca.n[2] = 4194304;
  ca.src[3] = Wq;    ca.dst[3] = Wqb; ca.n[3] = 1048576;
  ca.src[4] = Wk;    ca.dst[4] = Wkb; ca.n[4] = 1048576;
  ca.src[5] = Wv;    ca.dst[5] = Wvb; ca.n[5] = 1048576;
  ca.src[6] = Wo;    ca.dst[6] = Wob; ca.n[6] = 1048576;
  cast_bf16_kernel<<<dim3(2048, 7), 256, 0, stream>>>(ca);

  QkvArgs qa;
  qa.A[0] = qb;  qa.B[0] = Wqb; qa.bias[0] = bq; qa.out[0] = Qh;
  qa.A[1] = kb;  qa.B[1] = Wkb; qa.bias[1] = bk; qa.out[1] = Kh;
  qa.A[2] = Wvb; qa.B[2] = vb;  qa.bias[2] = bv; qa.out[2] = Vt;
  qkv_gemm<<<dim3(256, 3), 256, 0, stream>>>(qa);

  attn_kernel<<<dim3(16, 32), 512, 0, stream>>>(Qh, Kh, Vt, gprob, maskp, xb);
  gemm_out<<<dim3(8, 32), 256, 0, stream>>>(xb, Wob, bo, (float*)d_out);
}

// Round 10
// 286.390 us; speedup vs baseline: 1.1333x; 1.1333x over previous
//
#include <hip/hip_runtime.h>
#include <hip/hip_bf16.h>
#include <stdint.h>

// B=2, S=2048, D=1024, H=16, DK=64
typedef __bf16 bf16x8 __attribute__((ext_vector_type(8)));
typedef float f32x4 __attribute__((ext_vector_type(4)));

#define QSCALE 0.1803368801111244f  // (1/8) * log2(e): softmax via exp2

__device__ __forceinline__ void gld16(const void* g, void* l) {
  // async global->LDS, 16B/lane. LDS dest must be wave-uniform base + lane*16.
  __builtin_amdgcn_global_load_lds(
      (__attribute__((address_space(1))) void*)(uintptr_t)(g),
      (__attribute__((address_space(3))) void*)(l), 16, 0, 0);
}

// ---------------- cast f32 -> bf16 (7 tensors, one launch) ----------------
struct CastArgs {
  const float* src[7];
  __bf16* dst[7];
  int n[7];
};

__global__ __launch_bounds__(256) void cast_bf16_kernel(CastArgs a) {
  const int t = blockIdx.y;
  const int i = (blockIdx.x * 256 + threadIdx.x) * 8;
  if (i >= a.n[t]) return;
  const float4* s = (const float4*)(a.src[t] + i);
  float4 v0 = s[0], v1 = s[1];
  bf16x8 o;
  o[0] = (__bf16)v0.x; o[1] = (__bf16)v0.y; o[2] = (__bf16)v0.z; o[3] = (__bf16)v0.w;
  o[4] = (__bf16)v1.x; o[5] = (__bf16)v1.y; o[6] = (__bf16)v1.z; o[7] = (__bf16)v1.w;
  *(bf16x8*)(a.dst[t] + i) = o;
}

// ---------------- fused Q/K/V projection GEMM ----------------
// v10: back to the proven 2-barrier structure (v9's 1-barrier dbuf was ~20us
// SLOWER: end-of-iter barrier drains vmcnt anyway, 2x LDS cut occupancy).
// Occupancy raised instead via 512 threads / 8 waves per 128^2 tile
// (each wave 32x64, acc[2][4]=32 VGPR) -> ~5-6 waves/SIMD vs 3.
// z=0: Q = xq @ Wq^T (scale QSCALE) -> [b][h][s][dk]
// z=1: K = xk @ Wk^T               -> [b][h][s][dk]
// z=2: V^T = Wv @ xv^T             -> [b][h][dk][s]
struct QkvArgs {
  const __bf16* A[3];
  const __bf16* B[3];
  const float* bias[3];
  __bf16* out[3];
};

__global__ __launch_bounds__(512) void qkv_gemm(QkvArgs args) {
  __shared__ __align__(16) __bf16 As[128 * 32];
  __shared__ __align__(16) __bf16 Bs[128 * 32];
  const int tid = threadIdx.x;
  const int z = blockIdx.y;
  const int bx = blockIdx.x;
  const int m0 = (z < 2 ? (bx >> 3) : (bx & 7)) * 128;
  const int n0 = (z < 2 ? (bx & 7) : (bx >> 3)) * 128;
  const __bf16* A = args.A[z];
  const __bf16* B = args.B[z];
  const float* bias = args.bias[z];
  __bf16* out = args.out[z];
  const float scale = (z == 0) ? QSCALE : 1.0f;

  const int lane = tid & 63, wid = tid >> 6;        // wid 0..7
  const int wm = (wid & 3) * 32, wn = (wid >> 2) * 64;
  const int l16 = lane & 15, quad = lane >> 4;

  // staging: 512 thr x 16B = one 128x32 bf16 tile per gld16
  const int sc = (tid & 3) ^ ((tid >> 2) & 3);  // swizzled source chunk
  const __bf16* ga = A + (size_t)(m0 + (tid >> 2)) * 1024 + sc * 8;
  const __bf16* gb = B + (size_t)(n0 + (tid >> 2)) * 1024 + sc * 8;
  char* lA = (char*)As + tid * 16;
  char* lB = (char*)Bs + tid * 16;
  const int a_off = (wm + l16) * 64 + ((quad ^ (l16 & 3)) * 16);
  const int b_off = (wn + l16) * 64 + ((quad ^ (l16 & 3)) * 16);

  f32x4 acc[2][4] = {};

  for (int k0 = 0; k0 < 1024; k0 += 32) {
    __syncthreads();
    gld16(ga + k0, lA);
    gld16(gb + k0, lB);
    __syncthreads();
    bf16x8 af[2], bfr[4];
#pragma unroll
    for (int mi = 0; mi < 2; ++mi)
      af[mi] = *(const bf16x8*)((const char*)As + a_off + mi * 1024);
#pragma unroll
    for (int ni = 0; ni < 4; ++ni)
      bfr[ni] = *(const bf16x8*)((const char*)Bs + b_off + ni * 1024);
#pragma unroll
    for (int mi = 0; mi < 2; ++mi)
#pragma unroll
      for (int ni = 0; ni < 4; ++ni)
        acc[mi][ni] = __builtin_amdgcn_mfma_f32_16x16x32_bf16(af[mi], bfr[ni],
                                                              acc[mi][ni], 0, 0, 0);
  }

  if (z < 2) {  // token-major -> [b][h][s][dk]
#pragma unroll
    for (int ni = 0; ni < 4; ++ni) {
      const int col = n0 + wn + ni * 16 + l16;
      const int h = col >> 6, dk = col & 63;
      const float bb = bias[col];
#pragma unroll
      for (int mi = 0; mi < 2; ++mi)
#pragma unroll
        for (int r = 0; r < 4; ++r) {
          const int row = m0 + wm + mi * 16 + quad * 4 + r;
          const int b = row >> 11, s = row & 2047;
          out[((size_t)(b * 16 + h) * 2048 + s) * 64 + dk] =
              (__bf16)((acc[mi][ni][r] + bb) * scale);
        }
    }
  } else {  // V: A=W (m=feature), B=X (n=token); store Vt[b][h][dk][s]
#pragma unroll
    for (int mi = 0; mi < 2; ++mi)
#pragma unroll
      for (int r = 0; r < 4; ++r) {
        const int rowm = m0 + wm + mi * 16 + quad * 4 + r;
        const int h = rowm >> 6, dk = rowm & 63;
        const float bb = bias[rowm];
#pragma unroll
        for (int ni = 0; ni < 4; ++ni) {
          const int coln = n0 + wn + ni * 16 + l16;
          const int b = coln >> 11, s = coln & 2047;
          out[((size_t)(b * 16 + h) * 64 + dk) * 2048 + s] =
              (__bf16)(acc[mi][ni][r] + bb);
        }
      }
  }
}

// ---------------- output projection GEMM (f32 out) ----------------
// v10: 2-barrier, 512 threads / 8 waves (was 256 thr -> 1 wave/SIMD at
// grid=256 blocks = 1 block/CU; now 2 waves/SIMD).
__global__ __launch_bounds__(512) void gemm_out(const __bf16* __restrict__ A,
                                                const __bf16* __restrict__ B,
                                                const float* __restrict__ bias,
                                                float* __restrict__ out) {
  __shared__ __align__(16) __bf16 As[128 * 32];
  __shared__ __align__(16) __bf16 Bs[128 * 32];
  const int tid = threadIdx.x;
  const int m0 = blockIdx.y * 128;
  const int n0 = blockIdx.x * 128;
  const int lane = tid & 63, wid = tid >> 6;        // wid 0..7
  const int wm = (wid & 3) * 32, wn = (wid >> 2) * 64;
  const int l16 = lane & 15, quad = lane >> 4;

  const int sc = (tid & 3) ^ ((tid >> 2) & 3);
  const __bf16* ga = A + (size_t)(m0 + (tid >> 2)) * 1024 + sc * 8;
  const __bf16* gb = B + (size_t)(n0 + (tid >> 2)) * 1024 + sc * 8;
  char* lA = (char*)As + tid * 16;
  char* lB = (char*)Bs + tid * 16;
  const int a_off = (wm + l16) * 64 + ((quad ^ (l16 & 3)) * 16);
  const int b_off = (wn + l16) * 64 + ((quad ^ (l16 & 3)) * 16);

  f32x4 acc[2][4] = {};

  for (int k0 = 0; k0 < 1024; k0 += 32) {
    __syncthreads();
    gld16(ga + k0, lA);
    gld16(gb + k0, lB);
    __syncthreads();
    bf16x8 af[2], bfr[4];
#pragma unroll
    for (int mi = 0; mi < 2; ++mi)
      af[mi] = *(const bf16x8*)((const char*)As + a_off + mi * 1024);
#pragma unroll
    for (int ni = 0; ni < 4; ++ni)
      bfr[ni] = *(const bf16x8*)((const char*)Bs + b_off + ni * 1024);
#pragma unroll
    for (int mi = 0; mi < 2; ++mi)
#pragma unroll
      for (int ni = 0; ni < 4; ++ni)
        acc[mi][ni] = __builtin_amdgcn_mfma_f32_16x16x32_bf16(af[mi], bfr[ni],
                                                              acc[mi][ni], 0, 0, 0);
  }

#pragma unroll
  for (int ni = 0; ni < 4; ++ni) {
    const int col = n0 + wn + ni * 16 + l16;
    const float bb = bias[col];
#pragma unroll
    for (int mi = 0; mi < 2; ++mi)
#pragma unroll
      for (int r = 0; r < 4; ++r) {
        const int row = m0 + wm + mi * 16 + quad * 4 + r;
        out[(size_t)row * 1024 + col] = acc[mi][ni][r] + bb;
      }
  }
}

// ---------------- flash attention (v6, proven ~100.5us) -------------------
//  * SWAPPED QK^T: p2 = mfma(K, Q) -> each lane holds P for its own q-row.
//  * K rows staged through sigma(m) -> P lands in PV A-frag order, V natural.
//  * g folds into the pack: pa[j] = (bf16)(em * g); lp one scalar/lane.
__global__ __launch_bounds__(512, 4) void attn_kernel(
    const __bf16* __restrict__ Qh, const __bf16* __restrict__ Kh,
    const __bf16* __restrict__ Vt, const float* __restrict__ gprob,
    const int* __restrict__ maskp, __bf16* __restrict__ xb) {
  __shared__ __align__(16) __bf16 Ks[2][64 * 64];
  __shared__ __align__(16) __bf16 Vs[2][64 * 64];  // Vt tile: [dk][s_rel]
  __shared__ unsigned long long mbits[32];

  const int tid = threadIdx.x;
  const int qt = blockIdx.x, bh = blockIdx.y;  // qt 0..15 (128 q-rows each)
  const int b = bh >> 4, h = bh & 15;
  const int q0 = qt * 128;
  const int lane = tid & 63, wid = tid >> 6, l16 = lane & 15, quad = lane >> 4;
  const size_t head_off = (size_t)bh * (2048 * 64);

  const int srow = tid >> 3;                 // staging row 0..63 (512 threads)
  const int sc8 = (tid & 7) ^ (srow & 7);    // swizzled source chunk
  const int fxor = (l16 & 7);                // frag-read chunk xor

  // sigma(m): K-row staging permutation making swapped-QK P registers land in
  // PV A-frag order.
  const int sig = ((srow & 16) << 1) + ((srow & 12) << 1) + ((srow & 32) >> 3) +
                  (srow & 3);

  const __bf16* gk0 = Kh + head_off + (size_t)sig * 64 + sc8 * 8;
  const __bf16* gv0 = Vt + head_off + (size_t)srow * 2048 + sc8 * 8;

  // prologue staging: K/V tile 0 into buffer 0 (one gld16 each, 512 thr x 16B)
  gld16(gk0, (char*)Ks + tid * 16);
  gld16(gv0, (char*)Vs + tid * 16);

  // Q B-fragments direct from global (col = q0+wid*16+l16, dk chunks quad*8, +32)
  bf16x8 aq[2];
  {
    const __bf16* gq = Qh + head_off + (size_t)(q0 + wid * 16 + l16) * 64 + quad * 8;
    aq[0] = *(const bf16x8*)(gq);
    aq[1] = *(const bf16x8*)(gq + 32);
  }

  int irow[4];
#pragma unroll
  for (int r = 0; r < 4; ++r) irow[r] = q0 + wid * 16 + quad * 4 + r;

  // g for lane's q-row (q0+wid*16+l16), cols quad*8+{0..7} and +32 (A-frag order)
  const float* gpl = gprob + (size_t)b * 2048 * 2048 +
                     (size_t)(q0 + wid * 16 + l16) * 2048 + quad * 8;
  float4 g0 = *(const float4*)(gpl);
  float4 g1 = *(const float4*)(gpl + 4);
  float4 g2 = *(const float4*)(gpl + 32);
  float4 g3 = *(const float4*)(gpl + 36);

  // one-time mask ballot: mbits[kt] bit j = mask[b][kt*64+j]; 8 waves x 4
  {
    const int* mr = maskp + b * 2048;
#pragma unroll
    for (int t = 0; t < 4; ++t) {
      const int kt2 = wid * 4 + t;
      const int mv = mr[kt2 * 64 + lane];
      const unsigned long long bal = __ballot(mv != 0);
      if (lane == 0) mbits[kt2] = bal;
    }
  }
  __syncthreads();  // drains prologue staging (vmcnt0) + mbits visible

  f32x4 o[4] = {};
  float lp = 0.f;

  // diagonal k-tile for this wave's 16 q-rows (wave-uniform)
  const int dkt = qt * 2 + (wid >> 2);
  // lane's q-row rel. to the 64-wide k-tile; diag iff kqbase == kbase(ni,r)
  const int kqbase = (wid & 3) * 16 + l16 - quad * 8;

  for (int kt = 0; kt < 32; ++kt) {
    const int cur = kt & 1;
    float4 gn0, gn1, gn2, gn3;
    if (kt < 31) {  // prefetch K/V tile kt+1 into alternate buffer + g(kt+1)
      const int nb = cur ^ 1;
      gld16(gk0 + (kt + 1) * 4096, (char*)Ks + nb * 8192 + tid * 16);
      gld16(gv0 + (kt + 1) * 64, (char*)Vs + nb * 8192 + tid * 16);
      const float* gn = gpl + (kt + 1) * 64;
      gn0 = *(const float4*)(gn);
      gn1 = *(const float4*)(gn + 4);
      gn2 = *(const float4*)(gn + 32);
      gn3 = *(const float4*)(gn + 36);
    }

    // mask bits for this k-tile, shifted to this lane's k-window
    const unsigned long long sh = mbits[kt] >> (quad * 8);
    const uint32_t shlo = (uint32_t)sh, shhi = (uint32_t)(sh >> 32);

    // QK^T SWAPPED: p2[ni][r] = P[q=own row][k = sigma-staged] in log2 domain
    f32x4 p2[4] = {};
#pragma unroll
    for (int kh = 0; kh < 2; ++kh)
#pragma unroll
      for (int ni = 0; ni < 4; ++ni) {
        bf16x8 bk = *(const bf16x8*)((const char*)Ks + cur * 8192 +
                                     (ni * 16 + l16) * 128 +
                                     (((kh * 4 + quad) ^ fxor) * 16));
        p2[ni] = __builtin_amdgcn_mfma_f32_16x16x32_bf16(bk, aq[kh], p2[ni], 0, 0, 0);
      }

    // softmax + g fold + pack straight into PV A-fragments.
    // element (ni,r) holds k' = (ni&1)*32 + quad*8 + (ni>>1)*4 + r
    const float gfl[16] = {g0.x, g0.y, g0.z, g0.w, g1.x, g1.y, g1.z, g1.w,
                           g2.x, g2.y, g2.z, g2.w, g3.x, g3.y, g3.z, g3.w};
    bf16x8 pa0, pa1;
    if (kt != dkt) {
#pragma unroll
      for (int ni = 0; ni < 4; ++ni)
#pragma unroll
        for (int r = 0; r < 4; ++r) {
          const int j = ((ni >> 1) << 2) + r;
          const float e = __builtin_exp2f(p2[ni][r]);
          const bool mk = (((ni & 1) ? shhi : shlo) >> j) & 1;
          const float em = mk ? e : 0.f;
          lp += em;
          const float pg = em * gfl[(ni & 1) * 8 + j];
          if (ni & 1) pa1[j] = (__bf16)pg; else pa0[j] = (__bf16)pg;
        }
    } else {  // diagonal tile: always attend to self
#pragma unroll
      for (int ni = 0; ni < 4; ++ni)
#pragma unroll
        for (int r = 0; r < 4; ++r) {
          const int j = ((ni >> 1) << 2) + r;
          const float e = __builtin_exp2f(p2[ni][r]);
          const bool mk = (((ni & 1) ? shhi : shlo) >> j) & 1;
          const bool diag = (kqbase == ((ni & 1) * 32 + j));
          const float em = (mk || diag) ? e : 0.f;
          lp += em;
          const float pg = em * gfl[(ni & 1) * 8 + j];
          if (ni & 1) pa1[j] = (__bf16)pg; else pa0[j] = (__bf16)pg;
        }
    }

    // O += (P .* g) @ V, P directly from registers (no LDS roundtrip)
#pragma unroll
    for (int kh = 0; kh < 2; ++kh) {
      const bf16x8 pa = kh ? pa1 : pa0;
#pragma unroll
      for (int ni = 0; ni < 4; ++ni) {
        bf16x8 bv = *(const bf16x8*)((const char*)Vs + cur * 8192 +
                                     (ni * 16 + l16) * 128 +
                                     (((kh * 4 + quad) ^ fxor) * 16));
        o[ni] = __builtin_amdgcn_mfma_f32_16x16x32_bf16(pa, bv, o[ni], 0, 0, 0);
      }
    }

    if (kt < 31) { g0 = gn0; g1 = gn1; g2 = gn2; g3 = gn3; }
    __syncthreads();  // end of iter: prev readers done + prefetch drained
  }

  // lp: lane holds partial sum for q-row (l16); total over the 4 quads, then
  // redistribute to output rows quad*4+r and write x = O / l
  lp += __shfl_xor(lp, 16);
  lp += __shfl_xor(lp, 32);
  float rinv[4];
#pragma unroll
  for (int r = 0; r < 4; ++r) rinv[r] = 1.f / __shfl(lp, quad * 4 + r);
#pragma unroll
  for (int ni = 0; ni < 4; ++ni) {
    const int dk = ni * 16 + l16;
#pragma unroll
    for (int r = 0; r < 4; ++r) {
      const float val = o[ni][r] * rinv[r];
      xb[((size_t)(b * 2048 + irow[r])) * 1024 + h * 64 + dk] = (__bf16)val;
    }
  }
}

extern "C" void kernel_launch(void* const* d_in, const int* in_sizes, int n_in,
                              void* d_out, int out_size, void* d_ws, size_t ws_size,
                              hipStream_t stream) {
  const float* query = (const float*)d_in[0];
  const float* key_  = (const float*)d_in[1];
  const float* value = (const float*)d_in[2];
  const float* gprob = (const float*)d_in[3];
  const int*   maskp = (const int*)d_in[4];
  const float* Wq = (const float*)d_in[5];
  const float* bq = (const float*)d_in[6];
  const float* Wk = (const float*)d_in[7];
  const float* bk = (const float*)d_in[8];
  const float* Wv = (const float*)d_in[9];
  const float* bv = (const float*)d_in[10];
  const float* Wo = (const float*)d_in[11];
  const float* bo = (const float*)d_in[12];

  char* ws = (char*)d_ws;
  const size_t MB = 1 << 20;
  __bf16* qb  = (__bf16*)(ws + 0 * MB);
  __bf16* kb  = (__bf16*)(ws + 8 * MB);
  __bf16* vb  = (__bf16*)(ws + 16 * MB);
  __bf16* Wqb = (__bf16*)(ws + 24 * MB);
  __bf16* Wkb = (__bf16*)(ws + 26 * MB);
  __bf16* Wvb = (__bf16*)(ws + 28 * MB);
  __bf16* Wob = (__bf16*)(ws + 30 * MB);
  __bf16* Qh  = (__bf16*)(ws + 32 * MB);
  __bf16* Kh  = (__bf16*)(ws + 40 * MB);
  __bf16* Vt  = (__bf16*)(ws + 48 * MB);
  __bf16* xb  = (__bf16*)(ws + 56 * MB);

  CastArgs ca;
  ca.src[0] = query; ca.dst[0] = qb;  ca.n[0] = 4194304;
  ca.src[1] = key_;  ca.dst[1] = kb;  ca.n[1] = 4194304;
  ca.src[2] = value; ca.dst[2] = vb;  ca.n[2] = 4194304;
  ca.src[3] = Wq;    ca.dst[3] = Wqb; ca.n[3] = 1048576;
  ca.src[4] = Wk;    ca.dst[4] = Wkb; ca.n[4] = 1048576;
  ca.src[5] = Wv;    ca.dst[5] = Wvb; ca.n[5] = 1048576;
  ca.src[6] = Wo;    ca.dst[6] = Wob; ca.n[6] = 1048576;
  cast_bf16_kernel<<<dim3(2048, 7), 256, 0, stream>>>(ca);

  QkvArgs qa;
  qa.A[0] = qb;  qa.B[0] = Wqb; qa.bias[0] = bq; qa.out[0] = Qh;
  qa.A[1] = kb;  qa.B[1] = Wkb; qa.bias[1] = bk; qa.out[1] = Kh;
  qa.A[2] = Wvb; qa.B[2] = vb;  qa.bias[2] = bv; qa.out[2] = Vt;
  qkv_gemm<<<dim3(256, 3), 512, 0, stream>>>(qa);

  attn_kernel<<<dim3(16, 32), 512, 0, stream>>>(Qh, Kh, Vt, gprob, maskp, xb);
  gemm_out<<<dim3(8, 32), 512, 0, stream>>>(xb, Wob, bo, (float*)d_out);
}